// Round 2
// baseline (658.684 us; speedup 1.0000x reference)
//
#include <hip/hip_runtime.h>
#include <stdint.h>
#include <math.h>

// OTLoss: ft(4096x1024), fs(4096x1024) fp32 -> (loss, P[4096x4096], M[4096x4096])
//
//  1) row-normalize ft, fs -> bf16 A, B
//  2) M_raw = A @ B^T via mfma_f32_16x16x32_bf16, 128x128 tiles, BK=64,
//     XOR-swizzled LDS (kills 8-way bank conflicts), global_load_lds width 16.
//     epilogue: atomic sum/sumsq + per-row max (ordered-uint atomicMax)
//  3) stats: mean, inv_std (ddof=1)
//  4) buildK: M_out = (M_raw-mean)*inv_std; K = exp((M_raw-rowmax)*inv_std) fp16
//  5) Sinkhorn: P = diag(u) K diag(v). ONE fused kernel per iteration:
//     derive v from prev t (quad-buffered t[4] avoids races), check convergence,
//     row-matvec u = r/(Kv) for a 16-row strip, scatter-add t = K^T u.
//  6) final fused pass -> w = 1/(Kv), s = K^T w; P_ij = K_ij*w_i/s_j; loss.

#define NN 4096
#define DIM 1024
#define OT_EPS_F 1e-6f
#define RC (1.0f/4096.0f)

typedef __bf16 bf16_t;
typedef _Float16 half_t;
typedef __bf16 bf16x8 __attribute__((ext_vector_type(8)));
typedef _Float16 halfx8 __attribute__((ext_vector_type(8)));
typedef _Float16 halfx4 __attribute__((ext_vector_type(4)));
typedef float floatx4 __attribute__((ext_vector_type(4)));

typedef __attribute__((address_space(1))) void gv_t;
typedef __attribute__((address_space(3))) void lv_t;

__device__ __forceinline__ uint32_t fkey(float x) {
  uint32_t b = __float_as_uint(x);
  return (b & 0x80000000u) ? ~b : (b | 0x80000000u);
}
__device__ __forceinline__ float funkey(uint32_t k) {
  uint32_t b = (k & 0x80000000u) ? (k & 0x7fffffffu) : ~k;
  return __uint_as_float(b);
}

__device__ __forceinline__ void gld_lds16(const void* g, void* lds_uniform) {
  uint32_t loff = (uint32_t)(uintptr_t)lds_uniform;
  loff = (uint32_t)__builtin_amdgcn_readfirstlane((int)loff);
  __builtin_amdgcn_global_load_lds((gv_t*)(uintptr_t)g, (lv_t*)(uintptr_t)loff, 16, 0, 0);
}

// ---------------- init: zero t0, s, rowmax, scal ----------------
__global__ void init_ws(float* t0, float* s, uint32_t* rowmaxKey, float* scal) {
  int i = blockIdx.x * 256 + threadIdx.x;
  if (i < NN) { t0[i] = 0.f; s[i] = 0.f; rowmaxKey[i] = 0u; }
  if (i < 7) ((uint32_t*)scal)[i] = 0u;  // sum, sumsq, mean, inv_std, lossAcc, done, pad
}

// ---------------- row normalize + bf16 cast (both inputs, one launch) ----------------
__global__ __launch_bounds__(256) void norm_rows2(const float* __restrict__ ft,
                                                  const float* __restrict__ fs,
                                                  bf16_t* __restrict__ A,
                                                  bf16_t* __restrict__ B) {
  int bid = blockIdx.x;
  const float* X = (bid < 1024) ? ft : fs;
  bf16_t* Y = (bid < 1024) ? A : B;
  int tid = threadIdx.x;
  int wave = tid >> 6, lane = tid & 63;
  int row = (bid & 1023) * 4 + wave;
  const float* xr = X + (size_t)row * DIM;
  float xv[16];
  float ss = 0.f;
#pragma unroll
  for (int k = 0; k < 16; k++) { xv[k] = xr[lane + 64 * k]; ss += xv[k] * xv[k]; }
#pragma unroll
  for (int off = 1; off < 64; off <<= 1) ss += __shfl_xor(ss, off, 64);
  float inv = rsqrtf(ss);
  bf16_t* yr = Y + (size_t)row * DIM;
#pragma unroll
  for (int k = 0; k < 16; k++) yr[lane + 64 * k] = (bf16_t)(xv[k] * inv);
}

// ---------------- GEMM: C = A @ B^T, BK=64, XOR-swizzled LDS ----------------
__global__ __launch_bounds__(256) void gemm_bt(const bf16_t* __restrict__ A,
                                               const bf16_t* __restrict__ B,
                                               float* __restrict__ C,
                                               float* __restrict__ scal,
                                               uint32_t* __restrict__ rowmaxKey) {
  __shared__ __align__(16) bf16_t As[128 * 64];
  __shared__ __align__(16) bf16_t Bs[128 * 64];
  int tid = threadIdx.x;
  int wave = tid >> 6, lane = tid & 63;
  int quad = lane >> 4, l16 = lane & 15;
  int bm = blockIdx.y, bn = blockIdx.x;
  int waveM = wave >> 1, waveN = wave & 1;
  floatx4 acc[4][4] = {};

  for (int k0 = 0; k0 < DIM; k0 += 64) {
#pragma unroll
    for (int t = 0; t < 4; t++) {
      int cbase = t * 256 + wave * 64;  // wave-uniform chunk base
      int c = cbase + lane;
      int row = c >> 3, kcs = c & 7;
      int kc = kcs ^ (row & 7);  // XOR swizzle: LDS[row][kcs] holds global chunk kc
      gld_lds16(A + (size_t)(bm * 128 + row) * DIM + (k0 + kc * 8), (char*)As + (size_t)cbase * 16);
      gld_lds16(B + (size_t)(bn * 128 + row) * DIM + (k0 + kc * 8), (char*)Bs + (size_t)cbase * 16);
    }
    __syncthreads();
#pragma unroll
    for (int s = 0; s < 2; s++) {
      bf16x8 af[4], bfr[4];
#pragma unroll
      for (int mt = 0; mt < 4; mt++) {
        int row = waveM * 64 + mt * 16 + l16;
        int kcs = (s * 4 + quad) ^ (l16 & 7);
        af[mt] = *(const bf16x8*)(As + row * 64 + kcs * 8);
      }
#pragma unroll
      for (int nt = 0; nt < 4; nt++) {
        int row = waveN * 64 + nt * 16 + l16;
        int kcs = (s * 4 + quad) ^ (l16 & 7);
        bfr[nt] = *(const bf16x8*)(Bs + row * 64 + kcs * 8);
      }
#pragma unroll
      for (int mt = 0; mt < 4; mt++)
#pragma unroll
        for (int nt = 0; nt < 4; nt++)
          acc[mt][nt] = __builtin_amdgcn_mfma_f32_16x16x32_bf16(af[mt], bfr[nt], acc[mt][nt], 0, 0, 0);
    }
    __syncthreads();
  }

  // epilogue: write C (fp32), accumulate sum/sumsq, per-row max
  // C/D layout (m89-verified): col = lane&15, row = quad*4 + reg
  float lsum = 0.f, lsq = 0.f;
#pragma unroll
  for (int mt = 0; mt < 4; mt++) {
#pragma unroll
    for (int r = 0; r < 4; r++) {
      int gi = bm * 128 + waveM * 64 + mt * 16 + quad * 4 + r;
      float rmax = -3.4e38f;
#pragma unroll
      for (int nt = 0; nt < 4; nt++) {
        float vv = acc[mt][nt][r];
        int gj = bn * 128 + waveN * 64 + nt * 16 + l16;
        C[(size_t)gi * NN + gj] = vv;
        lsum += vv;
        lsq += vv * vv;
        rmax = fmaxf(rmax, vv);
      }
#pragma unroll
      for (int off = 1; off < 16; off <<= 1) rmax = fmaxf(rmax, __shfl_xor(rmax, off, 64));
      if (l16 == 0) atomicMax(rowmaxKey + gi, fkey(rmax));
    }
  }
#pragma unroll
  for (int off = 1; off < 64; off <<= 1) {
    lsum += __shfl_xor(lsum, off, 64);
    lsq += __shfl_xor(lsq, off, 64);
  }
  if (lane == 0) { atomicAdd(&scal[0], lsum); atomicAdd(&scal[1], lsq); }
}

// ---------------- mean / inv_std ----------------
__global__ void stats_kernel(float* scal) {
  double sum = (double)scal[0], sumsq = (double)scal[1];
  double N = (double)NN * (double)NN;
  double mean = sum / N;
  double var = (sumsq - sum * sum / N) / (N - 1.0);  // ddof=1
  scal[2] = (float)mean;
  scal[3] = (float)(1.0 / sqrt(var));
}

// ---------------- standardize M in place + build K fp16 ----------------
__global__ __launch_bounds__(256) void build_k(float* __restrict__ M, half_t* __restrict__ K,
                                               const float* __restrict__ scal,
                                               const uint32_t* __restrict__ rowmaxKey) {
  int row = blockIdx.x;
  float mean = scal[2], inv_std = scal[3];
  float rmaxraw = funkey(rowmaxKey[row]);
  float* mrow = M + (size_t)row * NN;
  half_t* krow = K + (size_t)row * NN;
  for (int j4 = threadIdx.x * 4; j4 < NN; j4 += 1024) {
    float raw[4];
    halfx4 kq;
#pragma unroll
    for (int q = 0; q < 4; q++) {
      raw[q] = mrow[j4 + q];
      mrow[j4 + q] = (raw[q] - mean) * inv_std;
      kq[q] = (half_t)__expf((raw[q] - rmaxraw) * inv_std);
    }
    *(halfx4*)(krow + j4) = kq;
  }
}

// ---------------- fused Sinkhorn iteration ----------------
// grid 256 blocks x 512 threads; block owns 16-row strip of K.
// it=0: v=1, accumulate t_out.  it=1..19: derive v from t_in (check conv vs
// vprev from t_in2), accumulate t_out, zero t_zero.  it=20 (final): u->u_out,
// t_out = s; runs even when done (uses frozen v_glob).
__global__ __launch_bounds__(512) void sinkhorn_fused(
    const half_t* __restrict__ Km, const float* __restrict__ t_in,
    const float* __restrict__ t_in2, float* __restrict__ t_out,
    float* __restrict__ t_zero, float* __restrict__ v_glob,
    float* __restrict__ u_out, uint32_t* __restrict__ done, int it) {
  int tid = threadIdx.x;
  int b = blockIdx.x;
  bool isfinal = (it >= 20);
  uint32_t dn = *done;
  if (!isfinal && dn) return;  // frozen: nothing to do (v_glob holds frozen v)

  __shared__ float v_lds[NN];
  __shared__ float u_lds[16];
  __shared__ float redsh[8];

  int j0 = tid * 8;
  float vv[8];
  if (isfinal && dn) {
#pragma unroll
    for (int k = 0; k < 8; k++) vv[k] = v_glob[j0 + k];
  } else if (it == 0) {
#pragma unroll
    for (int k = 0; k < 8; k++) vv[k] = 1.0f;
  } else {
    float tcur[8], vprev[8];
#pragma unroll
    for (int k = 0; k < 8; k++) tcur[k] = t_in[j0 + k];
    if (it == 1) {
#pragma unroll
      for (int k = 0; k < 8; k++) vprev[k] = 1.0f;
    } else {
#pragma unroll
      for (int k = 0; k < 8; k++) vprev[k] = RC / t_in2[j0 + k];
    }
    float md = 0.f;
#pragma unroll
    for (int k = 0; k < 8; k++) md = fmaxf(md, fabsf(vprev[k] * tcur[k] - RC));
#pragma unroll
    for (int off = 1; off < 64; off <<= 1) md = fmaxf(md, __shfl_xor(md, off, 64));
    int wv = tid >> 6, ln = tid & 63;
    if (ln == 0) redsh[wv] = md;
    __syncthreads();
    float mdall = fmaxf(fmaxf(fmaxf(redsh[0], redsh[1]), fmaxf(redsh[2], redsh[3])),
                        fmaxf(fmaxf(redsh[4], redsh[5]), fmaxf(redsh[6], redsh[7])));
    if (mdall <= OT_EPS_F) {
      if (!isfinal) {
        // converged at iteration it-1: freeze v = vprev into v_glob (disjoint slices)
        if (tid == 0) *done = 1u;
        if (tid < 16) {
          int j = b * 16 + tid;
          v_glob[j] = (it == 1) ? 1.0f : RC / t_in2[j];
        }
        return;
      }
#pragma unroll
      for (int k = 0; k < 8; k++) vv[k] = vprev[k];
    } else {
#pragma unroll
      for (int k = 0; k < 8; k++) vv[k] = RC / tcur[k];
    }
  }
#pragma unroll
  for (int k = 0; k < 8; k++) v_lds[j0 + k] = vv[k];
  if (t_zero && tid < 16) t_zero[b * 16 + tid] = 0.f;  // zero next iter's accumulator
  __syncthreads();

  // row pass: u_i = RC / sum_j K_ij v_j  (2 rows per wave)
  int strip0 = b * 16;
  int wv = tid >> 6, ln = tid & 63;
  const float4* v4 = (const float4*)v_lds;
#pragma unroll
  for (int rr = 0; rr < 2; rr++) {
    int i = strip0 + wv * 2 + rr;
    const halfx8* kr = (const halfx8*)(Km + (size_t)i * NN);
    float acc = 0.f;
#pragma unroll
    for (int c = 0; c < 8; c++) {
      int idx = c * 64 + ln;
      halfx8 kv = kr[idx];
      float4 va = v4[idx * 2], vb = v4[idx * 2 + 1];
      acc += (float)kv[0] * va.x + (float)kv[1] * va.y + (float)kv[2] * va.z + (float)kv[3] * va.w +
             (float)kv[4] * vb.x + (float)kv[5] * vb.y + (float)kv[6] * vb.z + (float)kv[7] * vb.w;
    }
#pragma unroll
    for (int off = 1; off < 64; off <<= 1) acc += __shfl_xor(acc, off, 64);
    if (ln == 0) {
      float uu = RC / acc;
      u_lds[wv * 2 + rr] = uu;
      if (u_out) u_out[i] = uu;
    }
  }
  __syncthreads();

  // col pass: t_out[j] += sum_{i in strip} K_ij u_i  (8 j per thread)
  float acc8[8] = {};
  const half_t* kp = Km + (size_t)strip0 * NN + j0;
#pragma unroll
  for (int i = 0; i < 16; i++) {
    halfx8 kv = *(const halfx8*)(kp + (size_t)i * NN);
    float ui = u_lds[i];
#pragma unroll
    for (int k = 0; k < 8; k++) acc8[k] += ui * (float)kv[k];
  }
#pragma unroll
  for (int k = 0; k < 8; k++) atomicAdd(t_out + j0 + k, acc8[k]);
}

// ---------------- invert s ----------------
__global__ void invert_s(float* s) {
  int i = blockIdx.x * 256 + threadIdx.x;
  s[i] = 1.0f / s[i];
}

// ---------------- final P write + loss ----------------
__global__ __launch_bounds__(256) void write_p(const half_t* __restrict__ K,
                                               const float* __restrict__ w,
                                               const float* __restrict__ sinv,
                                               float* __restrict__ P,
                                               float* __restrict__ lossAcc) {
  int row = blockIdx.x;
  float wi = w[row];
  const half_t* kr = K + (size_t)row * NN;
  float* pr = P + (size_t)row * NN;  // d_out+1 base: 4B-aligned only, scalar stores
  float ls = 0.f;
  for (int j = threadIdx.x; j < NN; j += 256) {
    float p = (float)kr[j] * wi * sinv[j];
    pr[j] = p;
    float d = p - ((j == row) ? 1.0f : 0.0f);
    ls += d * d;
  }
#pragma unroll
  for (int off = 1; off < 64; off <<= 1) ls += __shfl_xor(ls, off, 64);
  __shared__ float r4[4];
  int wave = threadIdx.x >> 6, lane = threadIdx.x & 63;
  if (lane == 0) r4[wave] = ls;
  __syncthreads();
  if (threadIdx.x == 0) atomicAdd(lossAcc, r4[0] + r4[1] + r4[2] + r4[3]);
}

__global__ void final_loss(float* out, const float* lossAcc) { out[0] = sqrtf(*lossAcc); }

// ---------------- launch ----------------
extern "C" void kernel_launch(void* const* d_in, const int* in_sizes, int n_in, void* d_out,
                              int out_size, void* d_ws, size_t ws_size, hipStream_t stream) {
  const float* ft = (const float*)d_in[0];
  const float* fs = (const float*)d_in[1];
  float* out = (float*)d_out;

  char* ws = (char*)d_ws;
  bf16_t* A = (bf16_t*)ws;                 //  8 MiB
  bf16_t* B = (bf16_t*)(ws + (8u << 20));  //  8 MiB
  half_t* K = (half_t*)(ws + (16u << 20)); // 32 MiB
  float* fbase = (float*)(ws + (48u << 20));
  float* tb[4] = {fbase, fbase + 4096, fbase + 8192, fbase + 12288};
  float* s = fbase + 16384;
  float* w = fbase + 20480;
  float* vg = fbase + 24576;
  uint32_t* rowmaxKey = (uint32_t*)(fbase + 28672);
  float* scal = fbase + 32768;  // [0]=sum [1]=sumsq [2]=mean [3]=inv_std [4]=lossAcc [5]=done
  uint32_t* done = (uint32_t*)(scal + 5);

  float* P_out = out + 1;
  float* M_out = out + 1 + (size_t)NN * NN;  // also scratch for M_raw

  init_ws<<<16, 256, 0, stream>>>(tb[0], s, rowmaxKey, scal);
  norm_rows2<<<2048, 256, 0, stream>>>(ft, fs, A, B);
  gemm_bt<<<dim3(32, 32), 256, 0, stream>>>(A, B, M_out, scal, rowmaxKey);
  stats_kernel<<<1, 1, 0, stream>>>(scal);
  build_k<<<NN, 256, 0, stream>>>(M_out, K, scal, rowmaxKey);

  sinkhorn_fused<<<256, 512, 0, stream>>>(K, nullptr, nullptr, tb[0], tb[1], vg, nullptr, done, 0);
  for (int it = 1; it < 20; it++) {
    sinkhorn_fused<<<256, 512, 0, stream>>>(K, tb[(it - 1) & 3], (it >= 2) ? tb[(it - 2) & 3] : nullptr,
                                            tb[it & 3], tb[(it + 1) & 3], vg, nullptr, done, it);
  }
  // final: w = RC/(Kv), s = K^T w (scale cancels in P)
  sinkhorn_fused<<<256, 512, 0, stream>>>(K, tb[3], tb[2], s, nullptr, vg, w, done, 20);
  invert_s<<<16, 256, 0, stream>>>(s);
  write_p<<<NN, 256, 0, stream>>>(K, w, s, P_out, scal + 4);
  final_loss<<<1, 1, 0, stream>>>(out, scal + 4);
}